// Round 7
// baseline (725.153 us; speedup 1.0000x reference)
//
#include <hip/hip_runtime.h>

#define B_  2
#define H_  16
#define S_  2048
#define D_  64
#define BH_ (B_*H_)
#define NKT (S_/64)
#define LDQ 72   // fallback kernel LDS stride

typedef __attribute__((ext_vector_type(8))) short bf16x8;
typedef __attribute__((ext_vector_type(4))) float f32x4;
typedef __attribute__((address_space(1))) const char gchar;
typedef __attribute__((address_space(3))) char lchar;

#define QK_SCALE 0.18033688011112042f   // (1/8) * log2(e)

static __device__ __forceinline__ ushort f2bf(float f) {
  union { float f; unsigned u; } v; v.f = f;
  unsigned r = (v.u + 0x7fff + ((v.u >> 16) & 1)) >> 16;  // RNE
  return (ushort)r;
}

static __device__ __forceinline__ uint4 pack8(const float* e, float sc) {
  uint4 p;
  p.x = (unsigned)f2bf(e[0]*sc) | ((unsigned)f2bf(e[1]*sc) << 16);
  p.y = (unsigned)f2bf(e[2]*sc) | ((unsigned)f2bf(e[3]*sc) << 16);
  p.z = (unsigned)f2bf(e[4]*sc) | ((unsigned)f2bf(e[5]*sc) << 16);
  p.w = (unsigned)f2bf(e[6]*sc) | ((unsigned)f2bf(e[7]*sc) << 16);
  return p;
}

// ============ kernel0: convert fp32 -> bf16, tile-order, XOR-granule-swizzled ============
// (verified on HW in round 5)
__global__ __launch_bounds__(256)
void conv_kernel(const float* __restrict__ Q, const float* __restrict__ K,
                 const float* __restrict__ V,
                 ushort* __restrict__ Qw, ushort* __restrict__ Kw, ushort* __restrict__ Vw)
{
  const int tile = blockIdx.x, bh = blockIdx.y, mode = blockIdx.z;
  const int tid = threadIdx.x;
  const float* src = (mode == 0 ? Q : (mode == 1 ? K : V)) + ((size_t)bh*S_ + tile*64) * D_;
  ushort* dst = (mode == 0 ? Qw : (mode == 1 ? Kw : Vw)) + ((size_t)bh*NKT + tile) * 4096;

  const int r  = tid >> 2;
  const int c0 = (tid & 3) * 16;

  if (mode < 2) {
    const float sc = (mode == 0) ? QK_SCALE : 1.0f;
    const float4* s4 = (const float4*)(src + (size_t)r*D_ + c0);
    float e[16];
#pragma unroll
    for (int i = 0; i < 4; ++i) {
      float4 v = s4[i];
      e[i*4+0] = v.x; e[i*4+1] = v.y; e[i*4+2] = v.z; e[i*4+3] = v.w;
    }
#pragma unroll
    for (int g = 0; g < 2; ++g) {
      const int gi = ((c0 >> 3) + g) ^ (r & 7);
      *(uint4*)((char*)dst + r*128 + gi*16) = pack8(e + g*8, sc);
    }
  } else {
    __shared__ float t[64][65];
    const float4* s4 = (const float4*)(src + (size_t)r*D_ + c0);
#pragma unroll
    for (int i = 0; i < 4; ++i) {
      float4 v = s4[i];
      t[r][c0 + i*4 + 0] = v.x; t[r][c0 + i*4 + 1] = v.y;
      t[r][c0 + i*4 + 2] = v.z; t[r][c0 + i*4 + 3] = v.w;
    }
    __syncthreads();
    float e[16];
#pragma unroll
    for (int i = 0; i < 16; ++i) e[i] = t[c0 + i][r];
#pragma unroll
    for (int g = 0; g < 2; ++g) {
      const int gi = ((c0 >> 3) + g) ^ (r & 7);
      *(uint4*)((char*)dst + r*128 + gi*16) = pack8(e + g*8, 1.0f);
    }
  }
}

// ============ async stage: one 8KB tile global -> LDS, linear ============
static __device__ __forceinline__ void stage8k(void* lds, const void* src, int wave, int lane) {
  const char* s = (const char*)src + lane*16;
  char* d = (char*)lds;
#pragma unroll
  for (int i = 0; i < 2; ++i) {
    const int off = (wave + i*4) << 10;
    __builtin_amdgcn_global_load_lds((gchar*)(s + off), (lchar*)(d + off), 16, 0, 0);
  }
}

// ============ main attention kernel: swapped QK^T, max-free softmax ============
__global__ __launch_bounds__(256, 3)
void attn3_kernel(const ushort* __restrict__ Qw, const ushort* __restrict__ Kw,
                  const ushort* __restrict__ Vw, const int* __restrict__ mask,
                  float* __restrict__ outO, float* __restrict__ outP)
{
  __shared__ ushort sQ[4096];
  __shared__ ushort sKV[4][4096];            // pass1: 2x(128-k dbuf); pass2: K dbuf [0..1], V dbuf [2..3]
  __shared__ __align__(16) ushort sP[4][1024];  // per-wave P [16q][64k] bf16, XOR-swizzled

  const int tid  = threadIdx.x;
  const int wave = tid >> 6;
  const int lane = tid & 63;
  const int l15  = lane & 15;
  const int lq   = lane >> 4;
  const int rxor = l15 & 7;

  const int qt = blockIdx.x;
  const int bh = blockIdx.y;
  const int b  = bh >> 4;

  const ushort* Qt = Qw + ((size_t)bh*NKT + qt) * 4096;
  const ushort* Kt = Kw + (size_t)bh*NKT * 4096;
  const ushort* Vt = Vw + (size_t)bh*NKT * 4096;
  const int*    mg = mask + b * S_;
  float* Og = outO + (size_t)(bh*S_ + qt*64) * D_;
  float* Pg = outP + (size_t)(bh*S_ + qt*64) * S_;

  stage8k(sQ, Qt, wave, lane);
  stage8k(sKV[0], Kt, wave, lane);
  stage8k(sKV[1], Kt + 4096, wave, lane);
  __syncthreads();

  // Q fragment (B-operand): lane holds Q[q=l15][d = lq*8 + e + 32c]
  bf16x8 qa[2];
#pragma unroll
  for (int c = 0; c < 2; ++c)
    qa[c] = *(const bf16x8*)((const char*)sQ + (wave*16 + l15)*128 + (((c*4 + lq) ^ rxor) << 4));

  // ---------- PASS 1: row sums only (no max), 128-k steps ----------
  float l_lane = 0.f;
  for (int kt2 = 0; kt2 < NKT/2; ++kt2) {
    const int cur2 = (kt2 & 1) * 2;
    if (kt2 + 1 < NKT/2) {
      stage8k(sKV[cur2 ^ 2],       Kt + (size_t)(2*kt2 + 2)*4096, wave, lane);
      stage8k(sKV[(cur2 ^ 2) + 1], Kt + (size_t)(2*kt2 + 3)*4096, wave, lane);
    }
#pragma unroll
    for (int t = 0; t < 8; ++t) {
      const char* rowp = (const char*)sKV[cur2 + (t >> 2)] + ((t & 3)*16 + l15)*128;
      const bf16x8 kb0 = *(const bf16x8*)(rowp + (((0 + lq) ^ rxor) << 4));
      const bf16x8 kb1 = *(const bf16x8*)(rowp + (((4 + lq) ^ rxor) << 4));
      f32x4 a = {0.f, 0.f, 0.f, 0.f};
      a = __builtin_amdgcn_mfma_f32_16x16x32_bf16(kb0, qa[0], a, 0, 0, 0);   // swapped: C[k][q]
      a = __builtin_amdgcn_mfma_f32_16x16x32_bf16(kb1, qa[1], a, 0, 0, 0);
      const int4 mv = *(const int4*)&mg[kt2*128 + t*16 + lq*4];
      if (mv.x == 0) a[0] = -1e30f;
      if (mv.y == 0) a[1] = -1e30f;
      if (mv.z == 0) a[2] = -1e30f;
      if (mv.w == 0) a[3] = -1e30f;
      l_lane += __builtin_amdgcn_exp2f(a[0]) + __builtin_amdgcn_exp2f(a[1])
              + __builtin_amdgcn_exp2f(a[2]) + __builtin_amdgcn_exp2f(a[3]);
    }
    __syncthreads();
  }

  // merge the 4 partial sums of q-row l15 (lanes l15+16k), then madj = log2(l)
  l_lane += __shfl_xor(l_lane, 16);
  l_lane += __shfl_xor(l_lane, 32);
  const float madj = __builtin_amdgcn_logf(l_lane);

  f32x4 oacc[4];
#pragma unroll
  for (int n = 0; n < 4; ++n) { oacc[n][0]=0.f; oacc[n][1]=0.f; oacc[n][2]=0.f; oacc[n][3]=0.f; }
  char* sPb = (char*)&sP[wave][0] + l15*128;   // this lane's q-row base

  // ---------- PASS 2: probs (direct from regs) + PV ----------
  stage8k(sKV[0], Kt, wave, lane);
  stage8k(sKV[2], Vt, wave, lane);
  __syncthreads();

  for (int kt = 0; kt < NKT; ++kt) {
    const int cur = kt & 1;
    if (kt + 1 < NKT) {
      stage8k(sKV[cur ^ 1],       Kt + (size_t)(kt + 1)*4096, wave, lane);
      stage8k(sKV[2 + (cur ^ 1)], Vt + (size_t)(kt + 1)*4096, wave, lane);
    }
#pragma unroll
    for (int t = 0; t < 4; ++t) {
      const char* rowp = (const char*)sKV[cur] + (t*16 + l15)*128;
      const bf16x8 kb0 = *(const bf16x8*)(rowp + (((0 + lq) ^ rxor) << 4));
      const bf16x8 kb1 = *(const bf16x8*)(rowp + (((4 + lq) ^ rxor) << 4));
      f32x4 a = {0.f, 0.f, 0.f, 0.f};
      a = __builtin_amdgcn_mfma_f32_16x16x32_bf16(kb0, qa[0], a, 0, 0, 0);
      a = __builtin_amdgcn_mfma_f32_16x16x32_bf16(kb1, qa[1], a, 0, 0, 0);
      const int4 mv = *(const int4*)&mg[kt*64 + t*16 + lq*4];
      if (mv.x == 0) a[0] = -1e30f;
      if (mv.y == 0) a[1] = -1e30f;
      if (mv.z == 0) a[2] = -1e30f;
      if (mv.w == 0) a[3] = -1e30f;
      // p = 2^(s - madj): lane holds P[q=l15][k = kt*64 + t*16 + lq*4 + j]
      f32x4 p;
      p[0] = __builtin_amdgcn_exp2f(a[0] - madj);
      p[1] = __builtin_amdgcn_exp2f(a[1] - madj);
      p[2] = __builtin_amdgcn_exp2f(a[2] - madj);
      p[3] = __builtin_amdgcn_exp2f(a[3] - madj);
      // probs store: float4 straight from registers
      *(f32x4*)&Pg[(size_t)(wave*16 + l15)*S_ + kt*64 + t*16 + lq*4] = p;
      // pack bf16x4 -> LDS for the PV A-fragment (XOR-swizzled, 2-way max)
      uint2 pk;
      pk.x = (unsigned)f2bf(p[0]) | ((unsigned)f2bf(p[1]) << 16);
      pk.y = (unsigned)f2bf(p[2]) | ((unsigned)f2bf(p[3]) << 16);
      *(uint2*)(sPb + ((t*32 + lq*8) ^ (rxor << 4))) = pk;
    }
    // PV: O[q][d] += P[q][k] * Vt[d][k]
#pragma unroll
    for (int c2 = 0; c2 < 2; ++c2) {
      const bf16x8 pa = *(const bf16x8*)(sPb + ((c2*64 + lq*16) ^ (rxor << 4)));
#pragma unroll
      for (int n = 0; n < 4; ++n) {
        const bf16x8 vb = *(const bf16x8*)((const char*)sKV[2 + cur] + (n*16 + l15)*128 + (((c2*4 + lq) ^ rxor) << 4));
        oacc[n] = __builtin_amdgcn_mfma_f32_16x16x32_bf16(pa, vb, oacc[n], 0, 0, 0);
      }
    }
    __syncthreads();
  }

#pragma unroll
  for (int n = 0; n < 4; ++n)
#pragma unroll
    for (int j = 0; j < 4; ++j)
      Og[(size_t)(wave*16 + lq*4 + j)*D_ + n*16 + l15] = oacc[n][j];
}

// ============ fallback: proven round-4 kernel (used only if ws too small) ============
static __device__ __forceinline__ void score_tiles_fb(
    f32x4 acc[4], const ushort* __restrict__ sK, const bf16x8 qa[2],
    int l15, int lq, const int* __restrict__ mg, int kbase)
{
#pragma unroll
  for (int t = 0; t < 4; ++t) {
    const bf16x8 kb0 = *(const bf16x8*)&sK[(t*16 + l15)*LDQ +      lq*8];
    const bf16x8 kb1 = *(const bf16x8*)&sK[(t*16 + l15)*LDQ + 32 + lq*8];
    f32x4 a = {0.f, 0.f, 0.f, 0.f};
    a = __builtin_amdgcn_mfma_f32_16x16x32_bf16(qa[0], kb0, a, 0, 0, 0);
    a = __builtin_amdgcn_mfma_f32_16x16x32_bf16(qa[1], kb1, a, 0, 0, 0);
    const int mv = mg[kbase + t*16 + l15];
    if (mv == 0) { a[0] = -1e30f; a[1] = -1e30f; a[2] = -1e30f; a[3] = -1e30f; }
    acc[t] = a;
  }
}

__global__ __launch_bounds__(256)
void attn_kernel(const float* __restrict__ Q, const float* __restrict__ K,
                 const float* __restrict__ V, const int* __restrict__ mask,
                 float* __restrict__ outO, float* __restrict__ outP)
{
  __shared__ ushort sQ[64 * LDQ];
  __shared__ ushort sK[64 * LDQ];
  __shared__ ushort sVt[D_ * LDQ];
  __shared__ ushort sP[4][16 * LDQ];

  const int tid  = threadIdx.x;
  const int wave = tid >> 6;
  const int lane = tid & 63;
  const int l15  = lane & 15;
  const int lq   = lane >> 4;
  const int qt = blockIdx.x;
  const int bh = blockIdx.y;
  const int b  = bh >> 4;
  const int q0 = qt * 64;

  const float* Qg = Q + (size_t)(bh*S_ + q0) * D_;
  const float* Kg = K + (size_t)bh * S_ * D_;
  const float* Vg = V + (size_t)bh * S_ * D_;
  const int*   mg = mask + b * S_;
  float* Og = outO + (size_t)(bh*S_ + q0) * D_;
  float* Pg = outP + ((size_t)(bh*S_ + q0)) * S_;

  const int srow = tid >> 2;
  const int sd0  = (tid & 3) * 16;

  {
    const float* src = Qg + (size_t)srow * D_ + sd0;
    ushort* dst = &sQ[srow*LDQ + sd0];
#pragma unroll
    for (int i = 0; i < 16; i += 4) {
      float4 v = *(const float4*)(src + i);
      dst[i+0] = f2bf(v.x * 0.125f); dst[i+1] = f2bf(v.y * 0.125f);
      dst[i+2] = f2bf(v.z * 0.125f); dst[i+3] = f2bf(v.w * 0.125f);
    }
  }
  __syncthreads();

  bf16x8 qa[2];
#pragma unroll
  for (int c = 0; c < 2; ++c)
    qa[c] = *(const bf16x8*)&sQ[(wave*16 + l15)*LDQ + c*32 + lq*8];

  float m_r[4] = {-1e30f, -1e30f, -1e30f, -1e30f};
  float l_r[4] = {0.f, 0.f, 0.f, 0.f};

  for (int kt = 0; kt < NKT; ++kt) {
    __syncthreads();
    {
      const float* src = Kg + (size_t)(kt*64 + srow) * D_ + sd0;
      ushort* dst = &sK[srow*LDQ + sd0];
#pragma unroll
      for (int i = 0; i < 16; i += 4) {
        float4 v = *(const float4*)(src + i);
        dst[i+0] = f2bf(v.x); dst[i+1] = f2bf(v.y);
        dst[i+2] = f2bf(v.z); dst[i+3] = f2bf(v.w);
      }
    }
    __syncthreads();
    f32x4 acc[4];
    score_tiles_fb(acc, sK, qa, l15, lq, mg, kt*64);
#pragma unroll
    for (int j = 0; j < 4; ++j) {
      float v = fmaxf(fmaxf(acc[0][j], acc[1][j]), fmaxf(acc[2][j], acc[3][j]));
#pragma unroll
      for (int s = 1; s < 16; s <<= 1) v = fmaxf(v, __shfl_xor(v, s));
      const float mn = fmaxf(m_r[j], v);
      float ps = __expf(acc[0][j] - mn) + __expf(acc[1][j] - mn)
               + __expf(acc[2][j] - mn) + __expf(acc[3][j] - mn);
#pragma unroll
      for (int s = 1; s < 16; s <<= 1) ps += __shfl_xor(ps, s);
      l_r[j] = l_r[j] * __expf(m_r[j] - mn) + ps;
      m_r[j] = mn;
    }
  }

  float inv_l[4];
#pragma unroll
  for (int j = 0; j < 4; ++j) inv_l[j] = 1.0f / l_r[j];

  f32x4 oacc[4];
#pragma unroll
  for (int n = 0; n < 4; ++n) { oacc[n][0]=0.f; oacc[n][1]=0.f; oacc[n][2]=0.f; oacc[n][3]=0.f; }
  ushort* sPw = &sP[wave][0];

  for (int kt = 0; kt < NKT; ++kt) {
    __syncthreads();
    {
      const float* src = Kg + (size_t)(kt*64 + srow) * D_ + sd0;
      ushort* dst = &sK[srow*LDQ + sd0];
#pragma unroll
      for (int i = 0; i < 16; i += 4) {
        float4 v = *(const float4*)(src + i);
        dst[i+0] = f2bf(v.x); dst[i+1] = f2bf(v.y);
        dst[i+2] = f2bf(v.z); dst[i+3] = f2bf(v.w);
      }
    }
    {
      const int vkey = tid & 63;
      const int vd0  = (tid >> 6) * 16;
      const float* vsrc = Vg + (size_t)(kt*64 + vkey) * D_ + vd0;
#pragma unroll
      for (int i = 0; i < 16; i += 4) {
        float4 v = *(const float4*)(vsrc + i);
        sVt[(vd0+i+0)*LDQ + vkey] = f2bf(v.x);
        sVt[(vd0+i+1)*LDQ + vkey] = f2bf(v.y);
        sVt[(vd0+i+2)*LDQ + vkey] = f2bf(v.z);
        sVt[(vd0+i+3)*LDQ + vkey] = f2bf(v.w);
      }
    }
    __syncthreads();
    f32x4 acc[4];
    score_tiles_fb(acc, sK, qa, l15, lq, mg, kt*64);
#pragma unroll
    for (int t = 0; t < 4; ++t)
#pragma unroll
      for (int j = 0; j < 4; ++j) {
        const float p = __expf(acc[t][j] - m_r[j]) * inv_l[j];
        sPw[(lq*4 + j)*LDQ + t*16 + l15] = f2bf(p);
      }
    __syncthreads();
#pragma unroll
    for (int i = 0; i < 4; ++i) {
      const int r = lq + i*4;
      const ushort* ps = &sPw[r*LDQ + l15*4];
      float4 o;
      o.x = __uint_as_float((unsigned)ps[0] << 16);
      o.y = __uint_as_float((unsigned)ps[1] << 16);
      o.z = __uint_as_float((unsigned)ps[2] << 16);
      o.w = __uint_as_float((unsigned)ps[3] << 16);
      *(float4*)&Pg[(size_t)(wave*16 + r)*S_ + kt*64 + l15*4] = o;
    }
#pragma unroll
    for (int c = 0; c < 2; ++c) {
      const bf16x8 pa = *(const bf16x8*)&sPw[l15*LDQ + c*32 + lq*8];
#pragma unroll
      for (int n = 0; n < 4; ++n) {
        const bf16x8 vb = *(const bf16x8*)&sVt[(n*16 + l15)*LDQ + c*32 + lq*8];
        oacc[n] = __builtin_amdgcn_mfma_f32_16x16x32_bf16(pa, vb, oacc[n], 0, 0, 0);
      }
    }
  }
#pragma unroll
  for (int n = 0; n < 4; ++n)
#pragma unroll
    for (int j = 0; j < 4; ++j)
      Og[(size_t)(wave*16 + lq*4 + j)*D_ + n*16 + l15] = oacc[n][j];
}

extern "C" void kernel_launch(void* const* d_in, const int* in_sizes, int n_in,
                              void* d_out, int out_size, void* d_ws, size_t ws_size,
                              hipStream_t stream) {
  const float* Q = (const float*)d_in[0];
  const float* K = (const float*)d_in[1];
  const float* V = (const float*)d_in[2];
  const int* mask = (const int*)d_in[3];
  float* outO = (float*)d_out;
  float* outP = outO + (size_t)B_ * H_ * S_ * D_;

  const size_t elems = (size_t)B_ * H_ * S_ * D_;
  if (ws_size >= elems * 2 * 3) {
    ushort* Qw = (ushort*)d_ws;
    ushort* Kw = Qw + elems;
    ushort* Vw = Kw + elems;
    conv_kernel<<<dim3(NKT, BH_, 3), dim3(256), 0, stream>>>(Q, K, V, Qw, Kw, Vw);
    attn3_kernel<<<dim3(S_/64, BH_), dim3(256), 0, stream>>>(Qw, Kw, Vw, mask, outO, outP);
  } else {
    attn_kernel<<<dim3(S_/64, BH_), dim3(256), 0, stream>>>(Q, K, V, mask, outO, outP);
  }
}

// Round 8
// 715.563 us; speedup vs baseline: 1.0134x; 1.0134x over previous
//
#include <hip/hip_runtime.h>

#define B_  2
#define H_  16
#define S_  2048
#define D_  64
#define BH_ (B_*H_)
#define NKT (S_/64)
#define LDQ 72   // fallback kernel LDS stride
#define LDP 72   // sP row stride (elements)

typedef __attribute__((ext_vector_type(8))) short bf16x8;
typedef __attribute__((ext_vector_type(4))) float f32x4;
typedef __attribute__((address_space(1))) const char gchar;
typedef __attribute__((address_space(3))) char lchar;

#define QK_SCALE 0.18033688011112042f   // (1/8) * log2(e)

static __device__ __forceinline__ ushort f2bf(float f) {
  union { float f; unsigned u; } v; v.f = f;
  unsigned r = (v.u + 0x7fff + ((v.u >> 16) & 1)) >> 16;  // RNE
  return (ushort)r;
}

static __device__ __forceinline__ uint4 pack8(const float* e, float sc) {
  uint4 p;
  p.x = (unsigned)f2bf(e[0]*sc) | ((unsigned)f2bf(e[1]*sc) << 16);
  p.y = (unsigned)f2bf(e[2]*sc) | ((unsigned)f2bf(e[3]*sc) << 16);
  p.z = (unsigned)f2bf(e[4]*sc) | ((unsigned)f2bf(e[5]*sc) << 16);
  p.w = (unsigned)f2bf(e[6]*sc) | ((unsigned)f2bf(e[7]*sc) << 16);
  return p;
}

// ============ kernel0: convert fp32 -> bf16, tile-order, XOR-granule-swizzled ============
// (HW-verified rounds 5/7)
__global__ __launch_bounds__(256)
void conv_kernel(const float* __restrict__ Q, const float* __restrict__ K,
                 const float* __restrict__ V,
                 ushort* __restrict__ Qw, ushort* __restrict__ Kw, ushort* __restrict__ Vw)
{
  const int tile = blockIdx.x, bh = blockIdx.y, mode = blockIdx.z;
  const int tid = threadIdx.x;
  const float* src = (mode == 0 ? Q : (mode == 1 ? K : V)) + ((size_t)bh*S_ + tile*64) * D_;
  ushort* dst = (mode == 0 ? Qw : (mode == 1 ? Kw : Vw)) + ((size_t)bh*NKT + tile) * 4096;

  const int r  = tid >> 2;
  const int c0 = (tid & 3) * 16;

  if (mode < 2) {
    const float sc = (mode == 0) ? QK_SCALE : 1.0f;
    const float4* s4 = (const float4*)(src + (size_t)r*D_ + c0);
    float e[16];
#pragma unroll
    for (int i = 0; i < 4; ++i) {
      float4 v = s4[i];
      e[i*4+0] = v.x; e[i*4+1] = v.y; e[i*4+2] = v.z; e[i*4+3] = v.w;
    }
#pragma unroll
    for (int g = 0; g < 2; ++g) {
      const int gi = ((c0 >> 3) + g) ^ (r & 7);
      *(uint4*)((char*)dst + r*128 + gi*16) = pack8(e + g*8, sc);
    }
  } else {
    __shared__ float t[64][65];
    const float4* s4 = (const float4*)(src + (size_t)r*D_ + c0);
#pragma unroll
    for (int i = 0; i < 4; ++i) {
      float4 v = s4[i];
      t[r][c0 + i*4 + 0] = v.x; t[r][c0 + i*4 + 1] = v.y;
      t[r][c0 + i*4 + 2] = v.z; t[r][c0 + i*4 + 3] = v.w;
    }
    __syncthreads();
    float e[16];
#pragma unroll
    for (int i = 0; i < 16; ++i) e[i] = t[c0 + i][r];
#pragma unroll
    for (int g = 0; g < 2; ++g) {
      const int gi = ((c0 >> 3) + g) ^ (r & 7);
      *(uint4*)((char*)dst + r*128 + gi*16) = pack8(e + g*8, 1.0f);
    }
  }
}

// ============ async stage: one 8KB tile global -> LDS, linear ============
static __device__ __forceinline__ void stage8k(void* lds, const void* src, int wave, int lane) {
  const char* s = (const char*)src + lane*16;
  char* d = (char*)lds;
#pragma unroll
  for (int i = 0; i < 2; ++i) {
    const int off = (wave + i*4) << 10;
    __builtin_amdgcn_global_load_lds((gchar*)(s + off), (lchar*)(d + off), 16, 0, 0);
  }
}

// ============ kernel1: row-sums -> madj[bh][q] = log2(sum_k 2^s) ============
// (= attn3 pass 1, HW-verified round 7; swapped MFMA, max-free sums)
__global__ __launch_bounds__(256, 3)
void sumk_kernel(const ushort* __restrict__ Qw, const ushort* __restrict__ Kw,
                 const int* __restrict__ mask, float* __restrict__ madj_g)
{
  __shared__ ushort sQ[4096];
  __shared__ ushort sKV[4][4096];

  const int tid  = threadIdx.x;
  const int wave = tid >> 6;
  const int lane = tid & 63;
  const int l15  = lane & 15;
  const int lq   = lane >> 4;
  const int rxor = l15 & 7;

  const int qt = blockIdx.x;
  const int bh = blockIdx.y;
  const int b  = bh >> 4;

  const ushort* Qt = Qw + ((size_t)bh*NKT + qt) * 4096;
  const ushort* Kt = Kw + (size_t)bh*NKT * 4096;
  const int*    mg = mask + b * S_;

  stage8k(sQ, Qt, wave, lane);
  stage8k(sKV[0], Kt, wave, lane);
  stage8k(sKV[1], Kt + 4096, wave, lane);
  __syncthreads();

  bf16x8 qa[2];
#pragma unroll
  for (int c = 0; c < 2; ++c)
    qa[c] = *(const bf16x8*)((const char*)sQ + (wave*16 + l15)*128 + (((c*4 + lq) ^ rxor) << 4));

  float l_lane = 0.f;
  for (int kt2 = 0; kt2 < NKT/2; ++kt2) {
    const int cur2 = (kt2 & 1) * 2;
    if (kt2 + 1 < NKT/2) {
      stage8k(sKV[cur2 ^ 2],       Kt + (size_t)(2*kt2 + 2)*4096, wave, lane);
      stage8k(sKV[(cur2 ^ 2) + 1], Kt + (size_t)(2*kt2 + 3)*4096, wave, lane);
    }
#pragma unroll
    for (int t = 0; t < 8; ++t) {
      const char* rowp = (const char*)sKV[cur2 + (t >> 2)] + ((t & 3)*16 + l15)*128;
      const bf16x8 kb0 = *(const bf16x8*)(rowp + (((0 + lq) ^ rxor) << 4));
      const bf16x8 kb1 = *(const bf16x8*)(rowp + (((4 + lq) ^ rxor) << 4));
      f32x4 a = {0.f, 0.f, 0.f, 0.f};
      a = __builtin_amdgcn_mfma_f32_16x16x32_bf16(kb0, qa[0], a, 0, 0, 0);   // swapped: C[k][q]
      a = __builtin_amdgcn_mfma_f32_16x16x32_bf16(kb1, qa[1], a, 0, 0, 0);
      const int4 mv = *(const int4*)&mg[kt2*128 + t*16 + lq*4];
      if (mv.x == 0) a[0] = -1e30f;
      if (mv.y == 0) a[1] = -1e30f;
      if (mv.z == 0) a[2] = -1e30f;
      if (mv.w == 0) a[3] = -1e30f;
      l_lane += __builtin_amdgcn_exp2f(a[0]) + __builtin_amdgcn_exp2f(a[1])
              + __builtin_amdgcn_exp2f(a[2]) + __builtin_amdgcn_exp2f(a[3]);
    }
    __syncthreads();
  }

  l_lane += __shfl_xor(l_lane, 16);
  l_lane += __shfl_xor(l_lane, 32);
  if (lane < 16)
    madj_g[(size_t)bh*S_ + qt*64 + wave*16 + lane] = __builtin_amdgcn_logf(l_lane);
}

// ============ kernel2: single pass — probs (coalesced 256B store) + PV ============
// (= attn2 pass 2, HW-verified round 5, with madj input instead of online stats)
__global__ __launch_bounds__(256, 3)
void attn4_kernel(const ushort* __restrict__ Qw, const ushort* __restrict__ Kw,
                  const ushort* __restrict__ Vw, const float* __restrict__ madj_g,
                  const int* __restrict__ mask,
                  float* __restrict__ outO, float* __restrict__ outP)
{
  __shared__ ushort sQ[4096];
  __shared__ ushort sKV[4][4096];           // K dbuf [0..1], V dbuf [2..3]
  __shared__ ushort sP[4][16 * LDP];        // per-wave P tile [16q][64k]

  const int tid  = threadIdx.x;
  const int wave = tid >> 6;
  const int lane = tid & 63;
  const int l15  = lane & 15;
  const int lq   = lane >> 4;
  const int rxor = l15 & 7;

  const int qt = blockIdx.x;
  const int bh = blockIdx.y;
  const int b  = bh >> 4;

  const ushort* Qt = Qw + ((size_t)bh*NKT + qt) * 4096;
  const ushort* Kt = Kw + (size_t)bh*NKT * 4096;
  const ushort* Vt = Vw + (size_t)bh*NKT * 4096;
  const int*    mg = mask + b * S_;
  float* Og = outO + (size_t)(bh*S_ + qt*64) * D_;
  float* Pg = outP + (size_t)(bh*S_ + qt*64) * S_;

  stage8k(sQ, Qt, wave, lane);
  stage8k(sKV[0], Kt, wave, lane);
  stage8k(sKV[2], Vt, wave, lane);
  __syncthreads();

  // Q fragment (A-operand, non-swapped): lane holds Q[q = wave*16+l15][d = c*32 + lq*8 + e]
  bf16x8 qa[2];
#pragma unroll
  for (int c = 0; c < 2; ++c)
    qa[c] = *(const bf16x8*)((const char*)sQ + (wave*16 + l15)*128 + (((c*4 + lq) ^ rxor) << 4));

  // per-lane madj for rows q = wave*16 + lq*4 + j
  const float4 mj = *(const float4*)&madj_g[(size_t)bh*S_ + qt*64 + wave*16 + lq*4];
  const float madj[4] = {mj.x, mj.y, mj.z, mj.w};

  f32x4 oacc[4];
#pragma unroll
  for (int n = 0; n < 4; ++n) { oacc[n][0]=0.f; oacc[n][1]=0.f; oacc[n][2]=0.f; oacc[n][3]=0.f; }
  ushort* sPw = &sP[wave][0];

  for (int kt = 0; kt < NKT; ++kt) {
    const int cur = kt & 1;
    if (kt + 1 < NKT) {
      stage8k(sKV[cur ^ 1],       Kt + (size_t)(kt + 1)*4096, wave, lane);
      stage8k(sKV[2 + (cur ^ 1)], Vt + (size_t)(kt + 1)*4096, wave, lane);
    }
    // QK^T: acc[t] covers keys t*16 + l15; rows q = lq*4 + j
    f32x4 acc[4];
#pragma unroll
    for (int t = 0; t < 4; ++t) {
      const char* rowp = (const char*)sKV[cur] + (t*16 + l15)*128;
      const bf16x8 kb0 = *(const bf16x8*)(rowp + (((0 + lq) ^ rxor) << 4));
      const bf16x8 kb1 = *(const bf16x8*)(rowp + (((4 + lq) ^ rxor) << 4));
      f32x4 a = {0.f, 0.f, 0.f, 0.f};
      a = __builtin_amdgcn_mfma_f32_16x16x32_bf16(qa[0], kb0, a, 0, 0, 0);
      a = __builtin_amdgcn_mfma_f32_16x16x32_bf16(qa[1], kb1, a, 0, 0, 0);
      const int mv = mg[kt*64 + t*16 + l15];
      if (mv == 0) { a[0] = -1e30f; a[1] = -1e30f; a[2] = -1e30f; a[3] = -1e30f; }
      acc[t] = a;
    }
    // p = 2^(s - madj) -> sP (bf16, wave-private, no barrier)
#pragma unroll
    for (int t = 0; t < 4; ++t) {
#pragma unroll
      for (int j = 0; j < 4; ++j) {
        sPw[(lq*4 + j)*LDP + t*16 + l15] = f2bf(__builtin_amdgcn_exp2f(acc[t][j] - madj[j]));
      }
    }
    // probs store: per i, 4 rows x 256B fully-contiguous segments
#pragma unroll
    for (int i = 0; i < 4; ++i) {
      const int r = lq + i*4;
      const ushort* ps = &sPw[r*LDP + l15*4];
      float4 o;
      o.x = __uint_as_float((unsigned)ps[0] << 16);
      o.y = __uint_as_float((unsigned)ps[1] << 16);
      o.z = __uint_as_float((unsigned)ps[2] << 16);
      o.w = __uint_as_float((unsigned)ps[3] << 16);
      *(float4*)&Pg[(size_t)(wave*16 + r)*S_ + kt*64 + l15*4] = o;
    }
    // PV: O[16q x 64d] += P[16q x 64k] * V[64k x 64d]
#pragma unroll
    for (int c2 = 0; c2 < 2; ++c2) {
      const bf16x8 pa = *(const bf16x8*)((const char*)sPw + l15*(LDP*2) + c2*64 + lq*16);
#pragma unroll
      for (int n = 0; n < 4; ++n) {
        const bf16x8 vb = *(const bf16x8*)((const char*)sKV[2 + cur] + (n*16 + l15)*128 + (((c2*4 + lq) ^ rxor) << 4));
        oacc[n] = __builtin_amdgcn_mfma_f32_16x16x32_bf16(pa, vb, oacc[n], 0, 0, 0);
      }
    }
    __syncthreads();
  }

#pragma unroll
  for (int n = 0; n < 4; ++n)
#pragma unroll
    for (int j = 0; j < 4; ++j)
      Og[(size_t)(wave*16 + lq*4 + j)*D_ + n*16 + l15] = oacc[n][j];
}

// ============ fallback: proven round-4 kernel (used only if ws too small) ============
static __device__ __forceinline__ void score_tiles_fb(
    f32x4 acc[4], const ushort* __restrict__ sK, const bf16x8 qa[2],
    int l15, int lq, const int* __restrict__ mg, int kbase)
{
#pragma unroll
  for (int t = 0; t < 4; ++t) {
    const bf16x8 kb0 = *(const bf16x8*)&sK[(t*16 + l15)*LDQ +      lq*8];
    const bf16x8 kb1 = *(const bf16x8*)&sK[(t*16 + l15)*LDQ + 32 + lq*8];
    f32x4 a = {0.f, 0.f, 0.f, 0.f};
    a = __builtin_amdgcn_mfma_f32_16x16x32_bf16(qa[0], kb0, a, 0, 0, 0);
    a = __builtin_amdgcn_mfma_f32_16x16x32_bf16(qa[1], kb1, a, 0, 0, 0);
    const int mv = mg[kbase + t*16 + l15];
    if (mv == 0) { a[0] = -1e30f; a[1] = -1e30f; a[2] = -1e30f; a[3] = -1e30f; }
    acc[t] = a;
  }
}

__global__ __launch_bounds__(256)
void attn_kernel(const float* __restrict__ Q, const float* __restrict__ K,
                 const float* __restrict__ V, const int* __restrict__ mask,
                 float* __restrict__ outO, float* __restrict__ outP)
{
  __shared__ ushort sQ[64 * LDQ];
  __shared__ ushort sK[64 * LDQ];
  __shared__ ushort sVt[D_ * LDQ];
  __shared__ ushort sP[4][16 * LDQ];

  const int tid  = threadIdx.x;
  const int wave = tid >> 6;
  const int lane = tid & 63;
  const int l15  = lane & 15;
  const int lq   = lane >> 4;
  const int qt = blockIdx.x;
  const int bh = blockIdx.y;
  const int b  = bh >> 4;
  const int q0 = qt * 64;

  const float* Qg = Q + (size_t)(bh*S_ + q0) * D_;
  const float* Kg = K + (size_t)bh * S_ * D_;
  const float* Vg = V + (size_t)bh * S_ * D_;
  const int*   mg = mask + b * S_;
  float* Og = outO + (size_t)(bh*S_ + q0) * D_;
  float* Pg = outP + ((size_t)(bh*S_ + q0)) * S_;

  const int srow = tid >> 2;
  const int sd0  = (tid & 3) * 16;

  {
    const float* src = Qg + (size_t)srow * D_ + sd0;
    ushort* dst = &sQ[srow*LDQ + sd0];
#pragma unroll
    for (int i = 0; i < 16; i += 4) {
      float4 v = *(const float4*)(src + i);
      dst[i+0] = f2bf(v.x * 0.125f); dst[i+1] = f2bf(v.y * 0.125f);
      dst[i+2] = f2bf(v.z * 0.125f); dst[i+3] = f2bf(v.w * 0.125f);
    }
  }
  __syncthreads();

  bf16x8 qa[2];
#pragma unroll
  for (int c = 0; c < 2; ++c)
    qa[c] = *(const bf16x8*)&sQ[(wave*16 + l15)*LDQ + c*32 + lq*8];

  float m_r[4] = {-1e30f, -1e30f, -1e30f, -1e30f};
  float l_r[4] = {0.f, 0.f, 0.f, 0.f};

  for (int kt = 0; kt < NKT; ++kt) {
    __syncthreads();
    {
      const float* src = Kg + (size_t)(kt*64 + srow) * D_ + sd0;
      ushort* dst = &sK[srow*LDQ + sd0];
#pragma unroll
      for (int i = 0; i < 16; i += 4) {
        float4 v = *(const float4*)(src + i);
        dst[i+0] = f2bf(v.x); dst[i+1] = f2bf(v.y);
        dst[i+2] = f2bf(v.z); dst[i+3] = f2bf(v.w);
      }
    }
    __syncthreads();
    f32x4 acc[4];
    score_tiles_fb(acc, sK, qa, l15, lq, mg, kt*64);
#pragma unroll
    for (int j = 0; j < 4; ++j) {
      float v = fmaxf(fmaxf(acc[0][j], acc[1][j]), fmaxf(acc[2][j], acc[3][j]));
#pragma unroll
      for (int s = 1; s < 16; s <<= 1) v = fmaxf(v, __shfl_xor(v, s));
      const float mn = fmaxf(m_r[j], v);
      float ps = __expf(acc[0][j] - mn) + __expf(acc[1][j] - mn)
               + __expf(acc[2][j] - mn) + __expf(acc[3][j] - mn);
#pragma unroll
      for (int s = 1; s < 16; s <<= 1) ps += __shfl_xor(ps, s);
      l_r[j] = l_r[j] * __expf(m_r[j] - mn) + ps;
      m_r[j] = mn;
    }
  }

  float inv_l[4];
#pragma unroll
  for (int j = 0; j < 4; ++j) inv_l[j] = 1.0f / l_r[j];

  f32x4 oacc[4];
#pragma unroll
  for (int n = 0; n < 4; ++n) { oacc[n][0]=0.f; oacc[n][1]=0.f; oacc[n][2]=0.f; oacc[n][3]=0.f; }
  ushort* sPw = &sP[wave][0];

  for (int kt = 0; kt < NKT; ++kt) {
    __syncthreads();
    {
      const float* src = Kg + (size_t)(kt*64 + srow) * D_ + sd0;
      ushort* dst = &sK[srow*LDQ + sd0];
#pragma unroll
      for (int i = 0; i < 16; i += 4) {
        float4 v = *(const float4*)(src + i);
        dst[i+0] = f2bf(v.x); dst[i+1] = f2bf(v.y);
        dst[i+2] = f2bf(v.z); dst[i+3] = f2bf(v.w);
      }
    }
    {
      const int vkey = tid & 63;
      const int vd0  = (tid >> 6) * 16;
      const float* vsrc = Vg + (size_t)(kt*64 + vkey) * D_ + vd0;
#pragma unroll
      for (int i = 0; i < 16; i += 4) {
        float4 v = *(const float4*)(vsrc + i);
        sVt[(vd0+i+0)*LDQ + vkey] = f2bf(v.x);
        sVt[(vd0+i+1)*LDQ + vkey] = f2bf(v.y);
        sVt[(vd0+i+2)*LDQ + vkey] = f2bf(v.z);
        sVt[(vd0+i+3)*LDQ + vkey] = f2bf(v.w);
      }
    }
    __syncthreads();
    f32x4 acc[4];
    score_tiles_fb(acc, sK, qa, l15, lq, mg, kt*64);
#pragma unroll
    for (int t = 0; t < 4; ++t)
#pragma unroll
      for (int j = 0; j < 4; ++j) {
        const float p = __expf(acc[t][j] - m_r[j]) * inv_l[j];
        sPw[(lq*4 + j)*LDQ + t*16 + l15] = f2bf(p);
      }
    __syncthreads();
#pragma unroll
    for (int i = 0; i < 4; ++i) {
      const int r = lq + i*4;
      const ushort* ps = &sPw[r*LDQ + l15*4];
      float4 o;
      o.x = __uint_as_float((unsigned)ps[0] << 16);
      o.y = __uint_as_float((unsigned)ps[1] << 16);
      o.z = __uint_as_float((unsigned)ps[2] << 16);
      o.w = __uint_as_float((unsigned)ps[3] << 16);
      *(float4*)&Pg[(size_t)(wave*16 + r)*S_ + kt*64 + l15*4] = o;
    }
#pragma unroll
    for (int c = 0; c < 2; ++c) {
      const bf16x8 pa = *(const bf16x8*)&sPw[l15*LDQ + c*32 + lq*8];
#pragma unroll
      for (int n = 0; n < 4; ++n) {
        const bf16x8 vb = *(const bf16x8*)&sVt[(n*16 + l15)*LDQ + c*32 + lq*8];
        oacc[n] = __builtin_amdgcn_mfma_f32_16x16x32_bf16(pa, vb, oacc[n], 0, 0, 0);
      }
    }
  }
#pragma unroll
  for (int n = 0; n < 4; ++n)
#pragma unroll
    for (int j = 0; j < 4; ++j)
      Og[(size_t)(wave*16 + lq*4 + j)*D_ + n*16 + l15] = oacc[n][j];
}

extern "C" void kernel_launch(void* const* d_in, const int* in_sizes, int n_in,
                              void* d_out, int out_size, void* d_ws, size_t ws_size,
                              hipStream_t stream) {
  const float* Q = (const float*)d_in[0];
  const float* K = (const float*)d_in[1];
  const float* V = (const float*)d_in[2];
  const int* mask = (const int*)d_in[3];
  float* outO = (float*)d_out;
  float* outP = outO + (size_t)B_ * H_ * S_ * D_;

  const size_t elems = (size_t)B_ * H_ * S_ * D_;      // 4,194,304 per tensor
  const size_t need = elems*2*3 + (size_t)BH_*S_*4;    // Qw,Kw,Vw + madj
  if (ws_size >= need) {
    ushort* Qw = (ushort*)d_ws;
    ushort* Kw = Qw + elems;
    ushort* Vw = Kw + elems;
    float* madj_g = (float*)(Vw + elems);
    conv_kernel<<<dim3(NKT, BH_, 3), dim3(256), 0, stream>>>(Q, K, V, Qw, Kw, Vw);
    sumk_kernel<<<dim3(S_/64, BH_), dim3(256), 0, stream>>>(Qw, Kw, mask, madj_g);
    attn4_kernel<<<dim3(S_/64, BH_), dim3(256), 0, stream>>>(Qw, Kw, Vw, madj_g, mask, outO, outP);
  } else {
    attn_kernel<<<dim3(S_/64, BH_), dim3(256), 0, stream>>>(Q, K, V, mask, outO, outP);
  }
}